// Round 3
// baseline (114.443 us; speedup 1.0000x reference)
//
#include <hip/hip_runtime.h>
#include <hip/hip_bf16.h>

#define KK 32
#define DD 512
#define BB 16
#define NN 4096
#define CHUNK 256
#define SUB 128
#define NCH 16

typedef __attribute__((ext_vector_type(8))) short short8;
typedef __attribute__((ext_vector_type(4))) float f32x4;

__device__ __forceinline__ unsigned short f2bf(float f) {
    unsigned u = __builtin_bit_cast(unsigned, f);
    u += 0x7fffu + ((u >> 16) & 1u);   // RNE bf16
    return (unsigned short)(u >> 16);
}

// x-tile swizzle: conflict-free for phase-A column reads, <=4-way for phase-B row reads
__device__ __forceinline__ int xswz(int row) {
    return ((row & 15) << 4) ^ (((row >> 3) & 3) << 5);
}

// ---------------- kernel 0: c2[k], s2[k], codes->bf16 ----------------
__global__ __launch_bounds__(256) void k_prep(const float* __restrict__ codes,
                                              const float* __restrict__ scale,
                                              float* __restrict__ c2w,
                                              float* __restrict__ s2w,
                                              unsigned short* __restrict__ codesb) {
    __shared__ float red[KK][8];
    int tid = threadIdx.x;
    int k = tid >> 3, pt = tid & 7;
    const float4* p = reinterpret_cast<const float4*>(codes + k * DD + pt * 64);
    ushort4* cb = reinterpret_cast<ushort4*>(codesb + k * DD + pt * 64);
    float s = 0.f;
#pragma unroll
    for (int i = 0; i < 16; ++i) {
        float4 v = p[i];
        s += v.x * v.x + v.y * v.y + v.z * v.z + v.w * v.w;
        ushort4 h;
        h.x = f2bf(v.x); h.y = f2bf(v.y); h.z = f2bf(v.z); h.w = f2bf(v.w);
        cb[i] = h;
    }
    red[k][pt] = s;
    __syncthreads();
    if (tid < KK) {
        float c2 = 0.f;
#pragma unroll
        for (int j = 0; j < 8; ++j) c2 += red[tid][j];
        c2w[tid] = c2;
        float sc = scale[tid];
        s2w[tid] = sc * sc;
    }
}

// ---------------- fused kernel: per (b, 256-token chunk) ----------------
// 512 threads (8 waves), x staged once into 128KB LDS, A never leaves the block.
__global__ __launch_bounds__(512, 1) void k_fused(const float* __restrict__ x,
                                                  const unsigned short* __restrict__ codesb,
                                                  const float* __restrict__ c2w,
                                                  const float* __restrict__ s2w,
                                                  float* __restrict__ part,
                                                  float* __restrict__ sAp) {
    __shared__ unsigned short xt[DD * SUB];        // 128 KB, swizzled [d][tok]
    __shared__ unsigned short alds[16 * 33 * 8];   // A bf16, padded [n/8][33][8]
    __shared__ float x2_lds[16][128];
    __shared__ float x2f[128];
    __shared__ float sA_lds[8][32];

    int tid = threadIdx.x;
    int lane = tid & 63;
    int w = tid >> 6;
    int g = lane >> 4, c = lane & 15;
    int bid = blockIdx.x;
    int b = bid >> 4;
    int chunk = bid & 15;

    int r16 = tid >> 5;    // 0..15 (staging row group)
    int q = tid & 31;      // staging float4 column
    const float* xb = x + (size_t)b * DD * NN + chunk * CHUNK + q * 4;
    char* xbp = reinterpret_cast<char*>(xt);

    float s2k0 = s2w[c], s2k1 = s2w[c + 16];
    float c2k0 = c2w[c], c2k1 = c2w[c + 16];

    f32x4 accB[2][4] = {};
    float pA0 = 0.f, pA1 = 0.f;

    // one phase-A K-step
    auto a_step = [&](int it, f32x4* accA) {
        short8 af;
#pragma unroll
        for (int j = 0; j < 8; ++j) {
            int row = it * 32 + g * 8 + j;
            af[j] = *reinterpret_cast<const short*>(
                xbp + (row << 8) + ((((w << 4) + c) << 1) ^ xswz(row)));
        }
        short8 b0 = *reinterpret_cast<const short8*>(codesb + (c << 9) + it * 32 + (g << 3));
        short8 b1 = *reinterpret_cast<const short8*>(codesb + ((c + 16) << 9) + it * 32 + (g << 3));
        accA[0] = __builtin_amdgcn_mfma_f32_16x16x32_bf16(af, b0, accA[0], 0, 0, 0);
        accA[1] = __builtin_amdgcn_mfma_f32_16x16x32_bf16(af, b1, accA[1], 0, 0, 0);
    };

    for (int s = 0; s < 2; ++s) {
        if (s) __syncthreads();          // phase-B(s-1) done -> x-tile free
        const float* xs = xb + s * SUB;
        float x2p0 = 0.f, x2p1 = 0.f, x2p2 = 0.f, x2p3 = 0.f;

        // ---- stage h1 (d 0..255): 16 float4 per thread
        float4 ld[16];
#pragma unroll
        for (int i = 0; i < 16; ++i)
            ld[i] = *reinterpret_cast<const float4*>(xs + (size_t)(r16 + 16 * i) * NN);
#pragma unroll
        for (int i = 0; i < 16; ++i) {
            int row = r16 + 16 * i;
            x2p0 += ld[i].x * ld[i].x; x2p1 += ld[i].y * ld[i].y;
            x2p2 += ld[i].z * ld[i].z; x2p3 += ld[i].w * ld[i].w;
            ushort4 h;
            h.x = f2bf(ld[i].x); h.y = f2bf(ld[i].y);
            h.z = f2bf(ld[i].z); h.w = f2bf(ld[i].w);
            *reinterpret_cast<ushort4*>(xbp + (row << 8) + (((q << 3)) ^ xswz(row))) = h;
        }
        __syncthreads();                 // h1 ready

        f32x4 accA[2] = {};

        // issue h2 batch1 (d 256..383), overlap with A-steps 0..3
        float4 l2[8];
#pragma unroll
        for (int i = 0; i < 8; ++i)
            l2[i] = *reinterpret_cast<const float4*>(xs + (size_t)(256 + r16 + 16 * i) * NN);
#pragma unroll
        for (int it = 0; it < 4; ++it) a_step(it, accA);
#pragma unroll
        for (int i = 0; i < 8; ++i) {
            int row = 256 + r16 + 16 * i;
            x2p0 += l2[i].x * l2[i].x; x2p1 += l2[i].y * l2[i].y;
            x2p2 += l2[i].z * l2[i].z; x2p3 += l2[i].w * l2[i].w;
            ushort4 h;
            h.x = f2bf(l2[i].x); h.y = f2bf(l2[i].y);
            h.z = f2bf(l2[i].z); h.w = f2bf(l2[i].w);
            *reinterpret_cast<ushort4*>(xbp + (row << 8) + (((q << 3)) ^ xswz(row))) = h;
        }
        // issue h2 batch2 (d 384..511), overlap with A-steps 4..7
#pragma unroll
        for (int i = 0; i < 8; ++i)
            l2[i] = *reinterpret_cast<const float4*>(xs + (size_t)(384 + r16 + 16 * i) * NN);
#pragma unroll
        for (int it = 4; it < 8; ++it) a_step(it, accA);
#pragma unroll
        for (int i = 0; i < 8; ++i) {
            int row = 384 + r16 + 16 * i;
            x2p0 += l2[i].x * l2[i].x; x2p1 += l2[i].y * l2[i].y;
            x2p2 += l2[i].z * l2[i].z; x2p3 += l2[i].w * l2[i].w;
            ushort4 h;
            h.x = f2bf(l2[i].x); h.y = f2bf(l2[i].y);
            h.z = f2bf(l2[i].z); h.w = f2bf(l2[i].w);
            *reinterpret_cast<ushort4*>(xbp + (row << 8) + (((q << 3)) ^ xswz(row))) = h;
        }
        *reinterpret_cast<float4*>(&x2_lds[r16][q * 4]) = make_float4(x2p0, x2p1, x2p2, x2p3);
        __syncthreads();                 // h2 + x2 partials ready

        if (tid < 128) {
            float ss = 0.f;
#pragma unroll
            for (int j = 0; j < 16; ++j) ss += x2_lds[j][tid];
            x2f[tid] = ss;
        }
#pragma unroll
        for (int it = 8; it < 16; ++it) a_step(it, accA);
        __syncthreads();                 // x2f ready

        // ---- softmax over k (lane-parallel across c), write A to LDS
#pragma unroll
        for (int r = 0; r < 4; ++r) {
            int tloc = w * 16 + g * 4 + r;
            float x2r = x2f[tloc];
            float d0v = s2k0 * (x2r - 2.f * accA[0][r] + c2k0);
            float d1v = s2k1 * (x2r - 2.f * accA[1][r] + c2k1);
            float m = fmaxf(d0v, d1v);
            m = fmaxf(m, __shfl_xor(m, 1));
            m = fmaxf(m, __shfl_xor(m, 2));
            m = fmaxf(m, __shfl_xor(m, 4));
            m = fmaxf(m, __shfl_xor(m, 8));
            float p0 = __expf(d0v - m), p1 = __expf(d1v - m);
            float ss = p0 + p1;
            ss += __shfl_xor(ss, 1);
            ss += __shfl_xor(ss, 2);
            ss += __shfl_xor(ss, 4);
            ss += __shfl_xor(ss, 8);
            float inv = 1.0f / ss;
            float a0 = p0 * inv, a1 = p1 * inv;
            alds[(tloc >> 3) * 264 + c * 8 + (tloc & 7)] = f2bf(a0);
            alds[(tloc >> 3) * 264 + (c + 16) * 8 + (tloc & 7)] = f2bf(a1);
            pA0 += a0;
            pA1 += a1;
        }
        __syncthreads();                 // alds ready

        // ---- phase-B: e += a^T x from LDS
#pragma unroll
        for (int nn = 0; nn < SUB; nn += 32) {
            int n8 = (nn >> 3) + g;
            short8 afa0 = *reinterpret_cast<const short8*>(alds + n8 * 264 + c * 8);
            short8 afa1 = *reinterpret_cast<const short8*>(alds + n8 * 264 + (c + 16) * 8);
#pragma unroll
            for (int dt = 0; dt < 4; ++dt) {
                int row = w * 64 + dt * 16 + c;
                short8 bx = *reinterpret_cast<const short8*>(
                    xbp + (row << 8) + ((((nn + g * 8)) << 1) ^ xswz(row)));
                accB[0][dt] = __builtin_amdgcn_mfma_f32_16x16x32_bf16(afa0, bx, accB[0][dt], 0, 0, 0);
                accB[1][dt] = __builtin_amdgcn_mfma_f32_16x16x32_bf16(afa1, bx, accB[1][dt], 0, 0, 0);
            }
        }
    }

    // ---- epilogue: sA partial + e-partial stores (no atomics)
    pA0 += __shfl_xor(pA0, 16); pA0 += __shfl_xor(pA0, 32);
    pA1 += __shfl_xor(pA1, 16); pA1 += __shfl_xor(pA1, 32);
    if (lane < 16) {
        sA_lds[w][c] = pA0;
        sA_lds[w][c + 16] = pA1;
    }
    __syncthreads();
    if (tid < 32) {
        float ss = 0.f;
#pragma unroll
        for (int j = 0; j < 8; ++j) ss += sA_lds[j][tid];
        sAp[(b * NCH + chunk) * KK + tid] = ss;
    }
    float* pp = part + (size_t)(b * NCH + chunk) * KK * DD;
#pragma unroll
    for (int kt = 0; kt < 2; ++kt)
#pragma unroll
        for (int dt = 0; dt < 4; ++dt)
#pragma unroll
            for (int r = 0; r < 4; ++r)
                pp[(kt * 16 + g * 4 + r) * DD + w * 64 + dt * 16 + c] = accB[kt][dt][r];
}

// ---------------- reduction: out = sum_chunks part - sA*codes ----------------
__global__ __launch_bounds__(256) void k_red(const float* __restrict__ part,
                                             const float* __restrict__ sAp,
                                             const float* __restrict__ codes,
                                             float* __restrict__ out) {
    int bid = blockIdx.x;        // b*32 + k
    int b = bid >> 5, k = bid & 31;
    int tid = threadIdx.x;
    int d = tid * 2;
    float sA = 0.f;
#pragma unroll
    for (int cc = 0; cc < NCH; ++cc) sA += sAp[(b * NCH + cc) * KK + k];
    const float* pb = part + (size_t)b * NCH * KK * DD + k * DD + d;
    float s0 = 0.f, s1 = 0.f;
#pragma unroll
    for (int cc = 0; cc < NCH; ++cc) {
        float2 v = *reinterpret_cast<const float2*>(pb + (size_t)cc * KK * DD);
        s0 += v.x; s1 += v.y;
    }
    float2 cd = *reinterpret_cast<const float2*>(codes + k * DD + d);
    float2 o;
    o.x = s0 - sA * cd.x;
    o.y = s1 - sA * cd.y;
    *reinterpret_cast<float2*>(out + ((size_t)b * KK + k) * DD + d) = o;
}

extern "C" void kernel_launch(void* const* d_in, const int* in_sizes, int n_in,
                              void* d_out, int out_size, void* d_ws, size_t ws_size,
                              hipStream_t stream) {
    const float* x = (const float*)d_in[0];
    const float* codes = (const float*)d_in[1];
    const float* scale = (const float*)d_in[2];
    float* out = (float*)d_out;
    float* ws = (float*)d_ws;

    float* sAp = ws;                                      // 512 f
    float* c2w = ws + 512;                                // 32
    float* s2w = ws + 544;                                // 32
    unsigned short* codesb = (unsigned short*)(ws + 576); // 32 KB bf16
    float* part = ws + 8768;                              // 16 MB partials (16-B aligned)

    k_prep<<<1, 256, 0, stream>>>(codes, scale, c2w, s2w, codesb);
    k_fused<<<BB * NCH, 512, 0, stream>>>(x, codesb, c2w, s2w, part, sAp);
    k_red<<<BB * KK, 256, 0, stream>>>(part, sAp, codes, out);
}

// Round 4
// 62.668 us; speedup vs baseline: 1.8262x; 1.8262x over previous
//
#include <hip/hip_runtime.h>
#include <hip/hip_bf16.h>

#define KK 32
#define DD 512
#define BB 16
#define NN 4096

typedef __attribute__((ext_vector_type(8))) short short8;
typedef __attribute__((ext_vector_type(4))) float f32x4;

__device__ __forceinline__ unsigned short f2bf(float f) {
    unsigned u = __builtin_bit_cast(unsigned, f);
    u += 0x7fffu + ((u >> 16) & 1u);   // RNE bf16
    return (unsigned short)(u >> 16);
}

// ---------------- kernel 0: c2[k], s2[k], codes->bf16 ----------------
__global__ __launch_bounds__(256) void k_prep(const float* __restrict__ codes,
                                              const float* __restrict__ scale,
                                              float* __restrict__ c2w,
                                              float* __restrict__ s2w,
                                              unsigned short* __restrict__ codesb) {
    __shared__ float red[KK][8];
    int tid = threadIdx.x;
    int k = tid >> 3, pt = tid & 7;
    const float4* p = reinterpret_cast<const float4*>(codes + k * DD + pt * 64);
    ushort4* cb = reinterpret_cast<ushort4*>(codesb + k * DD + pt * 64);
    float s = 0.f;
#pragma unroll
    for (int i = 0; i < 16; ++i) {
        float4 v = p[i];
        s += v.x * v.x + v.y * v.y + v.z * v.z + v.w * v.w;
        ushort4 h;
        h.x = f2bf(v.x); h.y = f2bf(v.y); h.z = f2bf(v.z); h.w = f2bf(v.w);
        cb[i] = h;
    }
    red[k][pt] = s;
    __syncthreads();
    if (tid < KK) {
        float c2 = 0.f;
#pragma unroll
        for (int j = 0; j < 8; ++j) c2 += red[tid][j];
        c2w[tid] = c2;
        float sc = scale[tid];
        s2w[tid] = sc * sc;
    }
}

// ---------------- pass A: softmax assignments A (bf16, packed) ----------------
// 256 threads (4 waves), 64 tokens/block, grid = 16*64 = 1024 (4 blocks/CU).
// LDS ~13 KB: x-tile double-buffer only; codes frags read from global (L2-hot).
__global__ __launch_bounds__(256) void k_assign(const float* __restrict__ x,
                                                const unsigned short* __restrict__ codesb,
                                                const float* __restrict__ c2w,
                                                const float* __restrict__ s2w,
                                                unsigned short* __restrict__ Aout,
                                                float* __restrict__ sAp) {
    __shared__ unsigned short xt[2][32 * 64];   // 2 x 4 KB, swizzled [d][tok]
    __shared__ float x2_lds[16][64];
    __shared__ float x2f[64];
    __shared__ float sA_lds[4][32];

    int tid = threadIdx.x;
    int lane = tid & 63;
    int w = tid >> 6;          // wave -> 16 tokens
    int g = lane >> 4, c = lane & 15;
    int bid = blockIdx.x;
    int b = bid >> 6;
    int chunk = bid & 63;
    int tok_base = chunk << 6;

    int srow = tid >> 4;       // 0..15
    int q = tid & 15;          // float4 token-column
    const float* xb = x + (size_t)b * DD * NN + tok_base + q * 4;

    float s2k0 = s2w[c], s2k1 = s2w[c + 16];
    float c2k0 = c2w[c], c2k1 = c2w[c + 16];

    f32x4 acc[2] = {};
    float x2p0 = 0.f, x2p1 = 0.f, x2p2 = 0.f, x2p3 = 0.f;
    float4 ld0, ld1;

    auto issue = [&](int it) {
        ld0 = *reinterpret_cast<const float4*>(xb + (size_t)(it * 32 + srow) * NN);
        ld1 = *reinterpret_cast<const float4*>(xb + (size_t)(it * 32 + srow + 16) * NN);
    };
    auto write_tile = [&](int buf) {
        char* bp = reinterpret_cast<char*>(&xt[buf][0]);
        x2p0 += ld0.x * ld0.x + ld1.x * ld1.x;
        x2p1 += ld0.y * ld0.y + ld1.y * ld1.y;
        x2p2 += ld0.z * ld0.z + ld1.z * ld1.z;
        x2p3 += ld0.w * ld0.w + ld1.w * ld1.w;
        ushort4 h0, h1;
        h0.x = f2bf(ld0.x); h0.y = f2bf(ld0.y); h0.z = f2bf(ld0.z); h0.w = f2bf(ld0.w);
        h1.x = f2bf(ld1.x); h1.y = f2bf(ld1.y); h1.z = f2bf(ld1.z); h1.w = f2bf(ld1.w);
        int r0 = srow, r1 = srow + 16;
        *reinterpret_cast<ushort4*>(bp + ((r0 << 7) + (q << 3) ^ (((r0 >> 3) & 3) << 5))) = h0;
        *reinterpret_cast<ushort4*>(bp + ((r1 << 7) + (q << 3) ^ (((r1 >> 3) & 3) << 5))) = h1;
    };

    issue(0);
    write_tile(0);
    __syncthreads();

    for (int it = 0; it < 16; ++it) {
        int cur = it & 1;
        if (it < 15) issue(it + 1);
        const char* bp = reinterpret_cast<const char*>(&xt[cur][0]);
        short8 af;
#pragma unroll
        for (int j = 0; j < 8; ++j) {
            int row = g * 8 + j;
            af[j] = *reinterpret_cast<const short*>(
                bp + (((row << 7) + ((w * 16 + c) << 1)) ^ (((row >> 3) & 3) << 5)));
        }
        short8 b0 = *reinterpret_cast<const short8*>(codesb + (c << 9) + it * 32 + (g << 3));
        short8 b1 = *reinterpret_cast<const short8*>(codesb + ((c + 16) << 9) + it * 32 + (g << 3));
        acc[0] = __builtin_amdgcn_mfma_f32_16x16x32_bf16(af, b0, acc[0], 0, 0, 0);
        acc[1] = __builtin_amdgcn_mfma_f32_16x16x32_bf16(af, b1, acc[1], 0, 0, 0);
        if (it < 15) write_tile(cur ^ 1);
        __syncthreads();
    }

    *reinterpret_cast<float4*>(&x2_lds[srow][q * 4]) = make_float4(x2p0, x2p1, x2p2, x2p3);
    __syncthreads();
    if (tid < 64) {
        float ss = 0.f;
#pragma unroll
        for (int j = 0; j < 16; ++j) ss += x2_lds[j][tid];
        x2f[tid] = ss;
    }
    __syncthreads();

    unsigned short* Ab = Aout + (size_t)b * NN * KK;
    float pA0 = 0.f, pA1 = 0.f;
#pragma unroll
    for (int r = 0; r < 4; ++r) {
        int tloc = w * 16 + g * 4 + r;
        float x2r = x2f[tloc];
        float d0v = s2k0 * (x2r - 2.f * acc[0][r] + c2k0);
        float d1v = s2k1 * (x2r - 2.f * acc[1][r] + c2k1);
        float m = fmaxf(d0v, d1v);
        m = fmaxf(m, __shfl_xor(m, 1));
        m = fmaxf(m, __shfl_xor(m, 2));
        m = fmaxf(m, __shfl_xor(m, 4));
        m = fmaxf(m, __shfl_xor(m, 8));
        float p0 = __expf(d0v - m), p1 = __expf(d1v - m);
        float ss = p0 + p1;
        ss += __shfl_xor(ss, 1);
        ss += __shfl_xor(ss, 2);
        ss += __shfl_xor(ss, 4);
        ss += __shfl_xor(ss, 8);
        float inv = 1.0f / ss;
        float a0 = p0 * inv, a1 = p1 * inv;
        int n = tok_base + tloc;
        unsigned short* pa = Ab + ((size_t)(n >> 3) << 8) + (n & 7);   // [n/8][k=32][n%8]
        pa[c * 8] = f2bf(a0);
        pa[(c + 16) * 8] = f2bf(a1);
        pA0 += a0;
        pA1 += a1;
    }
    pA0 += __shfl_xor(pA0, 16); pA0 += __shfl_xor(pA0, 32);
    pA1 += __shfl_xor(pA1, 16); pA1 += __shfl_xor(pA1, 32);
    if (lane < 16) {
        sA_lds[w][c] = pA0;
        sA_lds[w][c + 16] = pA1;
    }
    __syncthreads();
    if (tid < 32) {
        float ss = sA_lds[0][tid] + sA_lds[1][tid] + sA_lds[2][tid] + sA_lds[3][tid];
        sAp[(b * 64 + chunk) * KK + tid] = ss;
    }
}

// ---------------- pass B: e-partials per (b, 256-tok chunk, d-half) ----------------
// 512 threads (8 waves), no LDS, no barriers, grid = 16*16*2 = 512. No atomics.
__global__ __launch_bounds__(512) void k_agg(const float* __restrict__ x,
                                             const unsigned short* __restrict__ Ain,
                                             float* __restrict__ part) {
    int tid = threadIdx.x;
    int lane = tid & 63;
    int w = tid >> 6;
    int g = lane >> 4, c = lane & 15;
    int bid = blockIdx.x;
    int b = bid >> 5;
    int nc = (bid >> 1) & 15;
    int dh = bid & 1;

    f32x4 acc[2][2] = {};
    const float* xb = x + (size_t)b * DD * NN;
    const unsigned short* Ab = Ain + (size_t)b * NN * KK;

#pragma unroll 2
    for (int nn = 0; nn < 256; nn += 32) {
        int n0 = nc * 256 + nn + g * 8;
        const unsigned short* pa = Ab + ((size_t)(n0 >> 3) << 8);
        short8 af0 = *reinterpret_cast<const short8*>(pa + c * 8);
        short8 af1 = *reinterpret_cast<const short8*>(pa + c * 8 + 128);
        short8 bfrag[2];
#pragma unroll
        for (int dt = 0; dt < 2; ++dt) {
            const float* px = xb + (size_t)(dh * 256 + w * 32 + dt * 16 + c) * NN + n0;
            float4 v0 = *reinterpret_cast<const float4*>(px);
            float4 v1 = *reinterpret_cast<const float4*>(px + 4);
            short8 t;
            t[0] = (short)f2bf(v0.x); t[1] = (short)f2bf(v0.y);
            t[2] = (short)f2bf(v0.z); t[3] = (short)f2bf(v0.w);
            t[4] = (short)f2bf(v1.x); t[5] = (short)f2bf(v1.y);
            t[6] = (short)f2bf(v1.z); t[7] = (short)f2bf(v1.w);
            bfrag[dt] = t;
        }
#pragma unroll
        for (int dt = 0; dt < 2; ++dt) {
            acc[0][dt] = __builtin_amdgcn_mfma_f32_16x16x32_bf16(af0, bfrag[dt], acc[0][dt], 0, 0, 0);
            acc[1][dt] = __builtin_amdgcn_mfma_f32_16x16x32_bf16(af1, bfrag[dt], acc[1][dt], 0, 0, 0);
        }
    }

    float* pp = part + ((size_t)(b * 16 + nc) * KK) * DD;
#pragma unroll
    for (int kt = 0; kt < 2; ++kt)
#pragma unroll
        for (int dt = 0; dt < 2; ++dt) {
            int d = dh * 256 + w * 32 + dt * 16 + c;
#pragma unroll
            for (int r = 0; r < 4; ++r)
                pp[(kt * 16 + g * 4 + r) * DD + d] = acc[kt][dt][r];
        }
}

// ---------------- reduce: out = sum_chunks part - sA*codes ----------------
__global__ __launch_bounds__(256) void k_red(const float* __restrict__ part,
                                             const float* __restrict__ sAp,
                                             const float* __restrict__ codes,
                                             float* __restrict__ out) {
    int bid = blockIdx.x;        // b*32 + k
    int b = bid >> 5, k = bid & 31;
    int tid = threadIdx.x;
    int d = tid * 2;
    float sA = 0.f;
    for (int cc = 0; cc < 64; ++cc) sA += sAp[(b * 64 + cc) * KK + k];   // uniform -> s_loads
    const float* pb = part + (size_t)b * 16 * KK * DD + k * DD + d;
    float s0 = 0.f, s1 = 0.f;
#pragma unroll
    for (int cc = 0; cc < 16; ++cc) {
        float2 v = *reinterpret_cast<const float2*>(pb + (size_t)cc * KK * DD);
        s0 += v.x; s1 += v.y;
    }
    float2 cd = *reinterpret_cast<const float2*>(codes + k * DD + d);
    float2 o;
    o.x = s0 - sA * cd.x;
    o.y = s1 - sA * cd.y;
    *reinterpret_cast<float2*>(out + ((size_t)b * KK + k) * DD + d) = o;
}

extern "C" void kernel_launch(void* const* d_in, const int* in_sizes, int n_in,
                              void* d_out, int out_size, void* d_ws, size_t ws_size,
                              hipStream_t stream) {
    const float* x = (const float*)d_in[0];
    const float* codes = (const float*)d_in[1];
    const float* scale = (const float*)d_in[2];
    float* out = (float*)d_out;
    float* ws = (float*)d_ws;

    float* sAp = ws;                                        // 16*64*32 = 32768 f
    float* c2w = ws + 32768;                                // 32
    float* s2w = ws + 32800;                                // 32
    unsigned short* codesb = (unsigned short*)(ws + 32832); // 32 KB bf16
    unsigned short* Abuf = (unsigned short*)(ws + 41024);   // B*N*K bf16 ~4.2 MB
    float* part = ws + 41024 + 1048576;                     // 16*16*32*512 f = 16.8 MB

    k_prep<<<1, 256, 0, stream>>>(codes, scale, c2w, s2w, codesb);
    k_assign<<<BB * 64, 256, 0, stream>>>(x, codesb, c2w, s2w, Abuf, sAp);
    k_agg<<<BB * 16 * 2, 512, 0, stream>>>(x, Abuf, part);
    k_red<<<BB * KK, 256, 0, stream>>>(part, sAp, codes, out);
}